// Round 18
// baseline (851.002 us; speedup 1.0000x reference)
//
#include <hip/hip_runtime.h>
#include <hip/hip_bf16.h>
#include <math.h>

typedef unsigned short u16;
typedef short bf16x8 __attribute__((ext_vector_type(8)));
typedef float f32x4 __attribute__((ext_vector_type(4)));
typedef float f32x16 __attribute__((ext_vector_type(16)));

// software RNE (cold prep path; reference-identical)
__device__ __forceinline__ u16 f2b(float f){
  union { float f; unsigned u; } c; c.f = f;
  unsigned u = c.u;
  unsigned r = (u + 0x7fffu + ((u >> 16) & 1u)) >> 16;
  return (u16)r;
}
// hardware RNE via __bf16 cast — same rounding as f2b
__device__ __forceinline__ u16 f2bh(float f){
  union { __bf16 b; u16 u; } c; c.b = (__bf16)f; return c.u;
}
__device__ __forceinline__ unsigned pack2(float a, float b){
  return (unsigned)f2bh(a) | ((unsigned)f2bh(b) << 16);
}
__device__ __forceinline__ float gelu_f(float x){
  return 0.5f * x * (1.0f + erff(x * 0.70710678118654752f));
}

// ---------------------------------------------------------------------------
// Weight prep (proven) + zero tail: blocks 320-328 zero out[2304], block 329
// zeroes flags[64] (48 set-flags + ticket counter at flags[48]).
// Elementwise blocks 0..311 write bf16 B-fragment order:
//   chunk for (n,k): ((((n>>4)*4+(k>>5))*4+((k>>3)&3))*16+(n&15))*8 + (k&7).
// wT elem offsets: Wproj@0 | Wq@16384 (x 1/sqrt(128)) | Wk@147456 |
// W~=Wv@Wh @278528 (MFMA blocks 312..319) | Wfc@540672 | Wc@573440.
// ---------------------------------------------------------------------------
__global__ __launch_bounds__(256) void prep_weights(
    const float* __restrict__ Wproj, const float* __restrict__ Wq,
    const float* __restrict__ Wk,    const float* __restrict__ Wv,
    const float* __restrict__ Whp,   const float* __restrict__ Wfc,
    const float* __restrict__ Wc,    u16* __restrict__ wT,
    float* __restrict__ out, int* __restrict__ flags)
{
  __shared__ __align__(16) u16 Ah[128*136];   // Wh_h^T : [n][d]
  __shared__ __align__(16) u16 Bv[128*136];   // Wv_h   : [k][d]
  int bid = blockIdx.x, tid = threadIdx.x;
  if (bid == 329) { if (tid < 64) flags[tid] = 0; return; }
  if (bid >= 320) {                      // zero the output accumulator
    int o = (bid - 320) * 256 + tid;
    if (o < 2304) out[o] = 0.0f;
    return;
  }
  if (bid < 312) {
    int cid = bid * 256 + tid;
    if (cid >= 34816 && cid < 67584) return;   // W~ region written by MFMA blocks
    int region, lh = 0, c;
    if      (cid < 2048)  { region = 0; c = cid; }
    else if (cid < 18432) { int o = cid - 2048;  region = 1; lh = o >> 11; c = o & 2047; }
    else if (cid < 34816) { int o = cid - 18432; region = 2; lh = o >> 11; c = o & 2047; }
    else if (cid < 71680) { int o = cid - 67584; region = 5; lh = o >> 11; c = o & 2047; }
    else                  { int o = cid - 71680; region = 6; lh = o >> 11; c = o & 2047; }
    int l16 = c & 15, quad = (c >> 4) & 3, ks = (c >> 6) & 3, nt = c >> 8;
    int n = nt * 16 + l16, kb = ks * 32 + quad * 8;
    int l = lh >> 2, hh = lh & 3;
    const float rs = 0.08838834764831845f;
    u16 tmp[8];
#pragma unroll
    for (int e = 0; e < 8; ++e) {
      int k = kb + e;
      float v;
      switch (region) {
        case 0: v = Wproj[k * 128 + n]; break;
        case 1: v = Wq[l * 65536 + k * 512 + hh * 128 + n] * rs; break;
        case 2: v = Wk[l * 65536 + k * 512 + hh * 128 + n]; break;
        case 5: v = Wfc[lh * 16384 + k * 128 + n]; break;
        default: v = Wc[k * 512 + lh * 128 + n]; break;
      }
      tmp[e] = f2b(v);
    }
    *(uint4*)(wT + (size_t)cid * 8) = *(uint4*)tmp;
    return;
  }
  // ---- W~_h^T = Wh_h^T @ Wv_h^T via bf16 MFMA (one block per (l,h)) ----
  int lhb = bid - 312; int l = lhb >> 2, hh = lhb & 3;
#pragma unroll
  for (int it = 0; it < 64; ++it) {
    int idx = it * 256 + tid;
    int a = idx & 127, b = idx >> 7;
    Ah[a * 136 + b] = f2b(Whp[l * 65536 + (hh * 128 + b) * 128 + a]);  // [n=a][d=b]
    Bv[b * 136 + a] = f2b(Wv[l * 65536 + b * 512 + hh * 128 + a]);     // [k=b][d=a]
  }
  __syncthreads();
  int wv = tid >> 6, lane = tid & 63, quad = lane >> 4, l16 = lane & 15;
  f32x4 acc[2][8] = {};
  for (int ks = 0; ks < 4; ++ks) {
    bf16x8 aF[2], bF[8];
#pragma unroll
    for (int i = 0; i < 2; ++i)
      aF[i] = *(const bf16x8*)(Ah + ((wv*2+i)*16 + l16)*136 + ks*32 + quad*8);
#pragma unroll
    for (int n = 0; n < 8; ++n)
      bF[n] = *(const bf16x8*)(Bv + (n*16 + l16)*136 + ks*32 + quad*8);
#pragma unroll
    for (int i = 0; i < 2; ++i)
#pragma unroll
      for (int n = 0; n < 8; ++n)
        acc[i][n] = __builtin_amdgcn_mfma_f32_16x16x32_bf16(aF[i], bF[n], acc[i][n], 0, 0, 0);
  }
  size_t base = 278528 + (size_t)lhb * 16384;
#pragma unroll
  for (int i = 0; i < 2; ++i)
#pragma unroll
    for (int n2 = 0; n2 < 8; ++n2)
#pragma unroll
      for (int g = 0; g < 4; ++g) {
        int n = (wv*2+i)*16 + quad*4 + g;   // row of W~^T
        int k = n2*16 + l16;                // col
        wT[base + (size_t)((((n>>4)*4 + (k>>5))*4 + ((k>>3)&3))*16 + (n&15))*8 + (k&7)]
            = f2b(acc[i][n2][g]);
      }
}

// ---------------------------------------------------------------------------
// Trunk helpers (proven R16/R17).
// ---------------------------------------------------------------------------
__device__ __forceinline__ void gemm_g(const u16* A, const u16* __restrict__ Bg,
    f32x4 (*acc)[4], int wr, int wc, int quad, int l16, int lane){
#pragma unroll
  for (int ks = 0; ks < 4; ++ks){
    bf16x8 aF[2], bF[4];
#pragma unroll
    for (int i = 0; i < 2; ++i)
      aF[i] = *(const bf16x8*)(A + ((wr*2+i)*16 + l16)*136 + ks*32 + quad*8);
#pragma unroll
    for (int n = 0; n < 4; ++n)
      bF[n] = *(const bf16x8*)(Bg + ((size_t)(((wc*4+n)*4 + ks)*64 + lane))*8);
#pragma unroll
    for (int i = 0; i < 2; ++i)
#pragma unroll
      for (int n = 0; n < 4; ++n)
        acc[i][n] = __builtin_amdgcn_mfma_f32_16x16x32_bf16(aF[i], bF[n], acc[i][n], 0, 0, 0);
  }
}

__device__ __forceinline__ void write_rm(u16* dst, f32x4 (*acc)[4],
                                         int wr, int wc, int quad, int l16){
#pragma unroll
  for (int i = 0; i < 2; ++i)
#pragma unroll
    for (int n = 0; n < 4; ++n)
#pragma unroll
      for (int g = 0; g < 4; ++g)
        dst[((wr*2+i)*16 + quad*4 + g)*136 + (wc*4+n)*16 + l16] = f2bh(acc[i][n][g]);
}

__device__ __forceinline__ void write_tr(u16* dst, f32x4 (*acc)[4],
                                         int wr, int wc, int quad, int l16){
#pragma unroll
  for (int i = 0; i < 2; ++i)
#pragma unroll
    for (int n = 0; n < 4; ++n)
#pragma unroll
      for (int g = 0; g < 4; ++g)
        dst[((wc*4+n)*16 + l16)*136 + (wr*2+i)*16 + quad*4 + g] = f2bh(acc[i][n][g]);
}

__device__ __forceinline__ void block_reduce2(float &s1, float &s2,
                                              float* red, int wv, int lane){
#pragma unroll
  for (int off = 1; off < 64; off <<= 1){
    s1 += __shfl_xor(s1, off, 64);
    s2 += __shfl_xor(s2, off, 64);
  }
  if (lane == 0){ red[wv*2] = s1; red[wv*2+1] = s2; }
  __syncthreads();
  s1 = red[0]+red[2]+red[4]+red[6]+red[8]+red[10]+red[12]+red[14];
  s2 = red[1]+red[3]+red[5]+red[7]+red[9]+red[11]+red[13]+red[15];
  __syncthreads();
}

// ---------------------------------------------------------------------------
// MEGA (cooperative, 256 blocks x 512 thr): blocks 0-47 run the proven R17
// trunk for their set, then release a per-set flag (threadfence = L2
// writeback -> memory-side; flags via agent-scope atomics). ALL blocks then
// work-steal (pair,head) cross items (2 per block: two 256-thread halves),
// spinning on the two set flags, fencing once per item, then running the
// proven op-direct cross body + fused final atomics into out.
// Producers never wait on consumers + co-residency => deadlock-free.
// ---------------------------------------------------------------------------
__global__ __launch_bounds__(512, 2) void mega(
    const float* __restrict__ x, const int* __restrict__ xsize,
    const u16* __restrict__ wT, u16* __restrict__ zg,
    const float* __restrict__ w2, float* __restrict__ out,
    int* __restrict__ flags)
{
  __shared__ __align__(16) u16 hA[128*136];
  __shared__ __align__(16) u16 qP[128*136];
  __shared__ __align__(16) u16 kB[128*136];
  __shared__ __align__(16) u16 vB[128*136];
  __shared__ float svalid[128];
  __shared__ float red[16];
  __shared__ int s_item;
  __shared__ float redx[8];
  int tid = threadIdx.x;
  int bid = blockIdx.x;
  int* counter = flags + 48;
  const float rs = 0.08838834764831845f;

  if (bid < 48) {
    // ===================== TRUNK PHASE (proven R17 body) ==================
    int wv = tid >> 6, lane = tid & 63, quad = lane >> 4, l16 = lane & 15;
    int wr = wv >> 1, wc = wv & 1;
    int s = bid;
    int sz = xsize[s]; if (sz < 1) sz = 1;
    int Mt = (sz + 15) >> 4, Mk = (sz + 31) >> 5;
    float den = (float)sz * 128.0f;

#pragma unroll
    for (int it = 0; it < 4; ++it) {
      int ch = tid + it * 512; int r = ch >> 4, cc = ch & 15;
      const float* p = x + ((size_t)s * 128 + r) * 128 + cc * 8;
      float4 u0 = *(const float4*)p, u1 = *(const float4*)(p + 4);
      int nz = (u0.x!=0.f)|(u0.y!=0.f)|(u0.z!=0.f)|(u0.w!=0.f)|
               (u1.x!=0.f)|(u1.y!=0.f)|(u1.z!=0.f)|(u1.w!=0.f);
      nz |= __shfl_xor(nz,1,64); nz |= __shfl_xor(nz,2,64);
      nz |= __shfl_xor(nz,4,64); nz |= __shfl_xor(nz,8,64);
      if ((tid & 15) == 0) svalid[r] = nz ? 1.f : 0.f;
      uint4 w;
      w.x = pack2(u0.x,u0.y); w.y = pack2(u0.z,u0.w);
      w.z = pack2(u1.x,u1.y); w.w = pack2(u1.z,u1.w);
      *(uint4*)(hA + r*136 + cc*8) = w;
    }
    __syncthreads();

    f32x4 hR[2][4];
    {
      f32x4 acc[2][4] = {};
      gemm_g(hA, wT, acc, wr, wc, quad, l16, lane);
      __syncthreads();
#pragma unroll
      for (int i = 0; i < 2; ++i)
#pragma unroll
        for (int n = 0; n < 4; ++n)
#pragma unroll
          for (int g = 0; g < 4; ++g) {
            int row = (wr*2+i)*16 + quad*4 + g;
            float gg = gelu_f(acc[i][n][g]) * svalid[row];
            hR[i][n][g] = gg;
            hA[row*136 + (wc*4+n)*16 + l16] = f2bh(gg);
          }
      __syncthreads();
    }

#pragma unroll 1
    for (int l = 0; l < 2; ++l) {
      f32x4 aR[2][4] = {};
#pragma unroll 1
      for (int hh = 0; hh < 4; ++hh) {
        int lh = l * 4 + hh;
        {
          f32x4 qa[2][4] = {};
          gemm_g(hA, wT + 16384 + lh*16384, qa, wr, wc, quad, l16, lane);
          write_rm(qP, qa, wr, wc, quad, l16);
        }
        {
          f32x4 ka[2][4] = {};
          gemm_g(hA, wT + 147456 + lh*16384, ka, wr, wc, quad, l16, lane);
          write_rm(kB, ka, wr, wc, quad, l16);
        }
        {
          f32x4 va[2][4] = {};
          gemm_g(hA, wT + 278528 + lh*16384, va, wr, wc, quad, l16, lane);
          write_tr(vB, va, wr, wc, quad, l16);
        }
        __syncthreads();                 // S_b: q,k,v'T staged
        if (wv < Mt) {
          bf16x8 qA[4];
#pragma unroll
          for (int ks = 0; ks < 4; ++ks)
            qA[ks] = *(const bf16x8*)(qP + (wv*16 + l16)*136 + ks*32 + quad*8);
          f32x4 sacc[8] = {};
#pragma unroll
          for (int ks = 0; ks < 4; ++ks) {
            bf16x8 bF[8];
#pragma unroll
            for (int j = 0; j < 8; ++j)
              if (j < Mt) bF[j] = *(const bf16x8*)(kB + (j*16+l16)*136 + ks*32 + quad*8);
#pragma unroll
            for (int j = 0; j < 8; ++j)
              if (j < Mt) sacc[j] = __builtin_amdgcn_mfma_f32_16x16x32_bf16(qA[ks], bF[j], sacc[j], 0, 0, 0);
          }
          for (int g = 0; g < 4; ++g) {
            float vals[8]; float rmax = -1e30f;
#pragma unroll
            for (int j = 0; j < 8; ++j)
              if (j < Mt) {
                float v = sacc[j][g];
                vals[j] = v;
                rmax = fmaxf(rmax, v);
              }
            for (int off = 1; off < 16; off <<= 1) rmax = fmaxf(rmax, __shfl_xor(rmax, off, 64));
            if (sz < 128) rmax = fmaxf(rmax, 0.0f);   // ref max includes pad zeros
            float rsum = 0.f;
#pragma unroll
            for (int j = 0; j < 8; ++j)
              if (j < Mt) {
                float e = (vals[j] != 0.0f) ? __expf(vals[j] - rmax) : 0.0f;
                vals[j] = e; rsum += e;
              }
            for (int off = 1; off < 16; off <<= 1) rsum += __shfl_xor(rsum, off, 64);
            float inv = 1.0f / (rsum + 1e-10f);
#pragma unroll
            for (int j = 0; j < 8; ++j)
              if (j < Mt) sacc[j][g] = vals[j] * inv;
          }
#pragma unroll
          for (int j = 0; j < 8; ++j)
            if (j < Mt)
#pragma unroll
              for (int g = 0; g < 4; ++g)
                qP[(wv*16 + quad*4 + g)*136 + j*16 + l16] = f2bh(sacc[j][g]);
        }
        __syncthreads();                 // S_c: P staged
#pragma unroll
        for (int i = 0; i < 2; ++i) {
          int mtile = wr*2 + i;
          if (mtile < Mt) {
            for (int ks = 0; ks < Mk; ++ks) {
              bf16x8 aF = *(const bf16x8*)(qP + (mtile*16 + l16)*136 + ks*32 + quad*8);
              bf16x8 bF[4];
#pragma unroll
              for (int n = 0; n < 4; ++n)
                bF[n] = *(const bf16x8*)(vB + ((wc*4+n)*16+l16)*136 + ks*32 + quad*8);
#pragma unroll
              for (int n = 0; n < 4; ++n)
                aR[i][n] = __builtin_amdgcn_mfma_f32_16x16x32_bf16(aF, bF[n], aR[i][n], 0, 0, 0);
            }
          }
        }
        __syncthreads();                 // S_a: PV reads done
      } // heads

      {
        float ls1 = 0.f, ls2 = 0.f;
#pragma unroll
        for (int i = 0; i < 2; ++i)
#pragma unroll
          for (int n = 0; n < 4; ++n)
#pragma unroll
            for (int g = 0; g < 4; ++g) {
              int row = (wr*2+i)*16 + quad*4 + g;
              float u = hR[i][n][g] + aR[i][n][g] * svalid[row];
              hR[i][n][g] = u;
              ls1 += u; ls2 += u * u;
            }
        block_reduce2(ls1, ls2, red, wv, lane);
        float mean = ls1 / den;
        float var = ls2 / den - mean * mean; if (var < 0.f) var = 0.f;
        float inv = 1.0f / (sqrtf(var) + 1e-8f);
#pragma unroll
        for (int i = 0; i < 2; ++i)
#pragma unroll
          for (int n = 0; n < 4; ++n)
#pragma unroll
            for (int g = 0; g < 4; ++g) {
              int row = (wr*2+i)*16 + quad*4 + g;
              float hn = (hR[i][n][g] - mean) * inv * svalid[row];
              hR[i][n][g] = hn;
              hA[row*136 + (wc*4+n)*16 + l16] = f2bh(hn);
            }
        __syncthreads();
      }
      {
        f32x4 fa[2][4] = {};
        gemm_g(hA, wT + 540672 + l*16384, fa, wr, wc, quad, l16, lane);
        float ls1 = 0.f, ls2 = 0.f;
#pragma unroll
        for (int i = 0; i < 2; ++i)
#pragma unroll
          for (int n = 0; n < 4; ++n)
#pragma unroll
            for (int g = 0; g < 4; ++g) {
              int row = (wr*2+i)*16 + quad*4 + g;
              float u = hR[i][n][g] + gelu_f(fa[i][n][g]) * svalid[row];
              hR[i][n][g] = u;
              ls1 += u; ls2 += u * u;
            }
        block_reduce2(ls1, ls2, red, wv, lane);
        float mean = ls1 / den;
        float var = ls2 / den - mean * mean; if (var < 0.f) var = 0.f;
        float inv = 1.0f / (sqrtf(var) + 1e-8f);
#pragma unroll
        for (int i = 0; i < 2; ++i)
#pragma unroll
          for (int n = 0; n < 4; ++n)
#pragma unroll
            for (int g = 0; g < 4; ++g) {
              int row = (wr*2+i)*16 + quad*4 + g;
              float hn = (hR[i][n][g] - mean) * inv * svalid[row];
              hR[i][n][g] = hn;
              hA[row*136 + (wc*4+n)*16 + l16] = f2bh(hn);
            }
        __syncthreads();
      }
    } // layers

    // z in fragment-chunk order
#pragma unroll 1
    for (int hh = 0; hh < 4; ++hh) {
      f32x4 za[2][4] = {};
      gemm_g(hA, wT + 573440 + hh*16384, za, wr, wc, quad, l16, lane);
      u16* zb = zg + (((size_t)s*4 + hh) << 14);
#pragma unroll
      for (int i = 0; i < 2; ++i)
#pragma unroll
        for (int n = 0; n < 4; ++n)
#pragma unroll
          for (int g = 0; g < 4; ++g) {
            int row = (wr*2+i)*16 + quad*4 + g;
            int col = (wc*4+n)*16 + l16;
            zb[(size_t)(((row>>5)*8 + (col>>4))*512 + ((col>>3)&1)*256
                        + (row&31)*8 + (col&7))] = f2bh(za[i][n][g]);
          }
    }
    __syncthreads();                     // all z stores complete (vmcnt drain)
    if (tid == 0) {
      __threadfence();                   // L2 writeback to memory-side
      __hip_atomic_store(flags + s, 1, __ATOMIC_RELEASE, __HIP_MEMORY_SCOPE_AGENT);
    }
  } // trunk phase

  // ===================== CROSS PHASE (work-stealing) ======================
  {
    int half = tid >> 8, t = tid & 255;
    int w4 = t >> 6, lane = t & 63;
    for (;;) {
      if (tid == 0) s_item = atomicAdd(counter, 2);
      __syncthreads();
      int base = s_item;
      if (base >= 4704) break;
      int item = base + half;
      bool active = item < 4704;
      int j = 0, i = 0, hh2 = 0;
      if (active) {
        int pr = item >> 2; hh2 = item & 3;
        float jf = (97.0f - sqrtf(9409.0f - 8.0f * (float)pr)) * 0.5f;
        j = (int)jf; if (j > 47) j = 47; if (j < 0) j = 0;
        while (j > 0 && j * 48 - (j * (j - 1)) / 2 > pr) --j;
        while ((j + 1) * 48 - ((j + 1) * j) / 2 <= pr) ++j;
        i = j + pr - (j * 48 - (j * (j - 1)) / 2);
        if (t == 0) {
          while (__hip_atomic_load(flags + j, __ATOMIC_ACQUIRE, __HIP_MEMORY_SCOPE_AGENT) == 0 ||
                 __hip_atomic_load(flags + i, __ATOMIC_ACQUIRE, __HIP_MEMORY_SCOPE_AGENT) == 0)
            __builtin_amdgcn_s_sleep(2);
        }
      }
      __syncthreads();                   // both halves' flags observed
      __threadfence();                   // acquire: invalidate stale caches
      float tp = 0.f;
      int sj = 1, si = 1;
      if (active) {
        sj = xsize[j]; if (sj < 1) sj = 1;
        si = xsize[i]; if (si < 1) si = 1;
        int MjT = (sj + 31) >> 5, MiT = (si + 31) >> 5;
        const u16* zj = zg + (((size_t)j * 4 + hh2) << 14);
        const u16* zi = zg + (((size_t)i * 4 + hh2) << 14);
        int gA = (w4 >> 1) * 2, gB = (w4 & 1) * 2;
        bool a0 = gA < MjT, a1 = (gA + 1) < MjT;
        bool b0 = gB < MiT, b1 = (gB + 1) < MiT;
        f32x16 acc[2][2] = {};
        if ((a0 || a1) && (b0 || b1)) {
#pragma unroll
          for (int ks = 0; ks < 8; ++ks) {
            bf16x8 aF[2], bF[2];
            if (a0) aF[0] = *(const bf16x8*)(zj + (size_t)((gA    )*8 + ks)*512 + lane*8);
            if (a1) aF[1] = *(const bf16x8*)(zj + (size_t)((gA + 1)*8 + ks)*512 + lane*8);
            if (b0) bF[0] = *(const bf16x8*)(zi + (size_t)((gB    )*8 + ks)*512 + lane*8);
            if (b1) bF[1] = *(const bf16x8*)(zi + (size_t)((gB + 1)*8 + ks)*512 + lane*8);
            if (a0 && b0) acc[0][0] = __builtin_amdgcn_mfma_f32_32x32x16_bf16(aF[0], bF[0], acc[0][0], 0, 0, 0);
            if (a0 && b1) acc[0][1] = __builtin_amdgcn_mfma_f32_32x32x16_bf16(aF[0], bF[1], acc[0][1], 0, 0, 0);
            if (a1 && b0) acc[1][0] = __builtin_amdgcn_mfma_f32_32x32x16_bf16(aF[1], bF[0], acc[1][0], 0, 0, 0);
            if (a1 && b1) acc[1][1] = __builtin_amdgcn_mfma_f32_32x32x16_bf16(aF[1], bF[1], acc[1][1], 0, 0, 0);
          }
        }
        float s1 = 0.f, s2 = 0.f;
#pragma unroll
        for (int ii = 0; ii < 2; ++ii)
#pragma unroll
          for (int jj = 0; jj < 2; ++jj) {
            bool tact = (ii ? a1 : a0) && (jj ? b1 : b0);
            if (tact)
#pragma unroll
              for (int r = 0; r < 16; ++r) {
                float a = acc[ii][jj][r];
                s1 += a; s2 += fabsf(a);
              }
          }
        tp = rs * (0.65f * s1 + 0.35f * s2);
        for (int off = 1; off < 64; off <<= 1) tp += __shfl_xor(tp, off, 64);
      }
      if (lane == 0) redx[half*4 + w4] = tp;
      __syncthreads();
      if (t == 0 && active) {
        float T = redx[half*4] + redx[half*4+1] + redx[half*4+2] + redx[half*4+3];
        float w = w2[hh2];
        atomicAdd(out + j * 48 + i, T * w / ((float)si * 128.0f));
        if (i != j)
          atomicAdd(out + i * 48 + j, T * w / ((float)sj * 128.0f));
      }
      __syncthreads();                   // redx / s_item safe for next round
    }
  }
}

// ---------------------------------------------------------------------------
extern "C" void kernel_launch(void* const* d_in, const int* in_sizes, int n_in,
                              void* d_out, int out_size, void* d_ws, size_t ws_size,
                              hipStream_t stream)
{
  const float* x     = (const float*)d_in[0];
  const int*   xsize = (const int*)d_in[1];
  const float* Wproj = (const float*)d_in[2];
  const float* Wq    = (const float*)d_in[3];
  const float* Wk    = (const float*)d_in[4];
  const float* Wv    = (const float*)d_in[5];
  const float* Whp   = (const float*)d_in[6];
  const float* Wfc   = (const float*)d_in[7];
  const float* Wc    = (const float*)d_in[8];
  const float* w2    = (const float*)d_in[9];
  float* out = (float*)d_out;

  char* ws = (char*)d_ws;
  size_t off = 0;
  auto alloc = [&](size_t bytes) -> char* {
    char* p = ws + off;
    off += (bytes + 255) & ~(size_t)255;
    return p;
  };
  u16* wT    = (u16*)alloc(638976 * 2);
  u16* zg    = (u16*)alloc((size_t)3145728 * 2);
  int* flags = (int*)alloc(64 * 4);       // 48 set-flags + counter @48

  prep_weights<<<330, 256, 0, stream>>>(Wproj, Wq, Wk, Wv, Whp, Wfc, Wc, wT, out, flags);

  {
    const float* xa = x; const int* xs = xsize; const u16* w = wT;
    u16* z = zg; const float* w2a = w2; float* oa = out; int* fl = flags;
    void* args[] = { (void*)&xa, (void*)&xs, (void*)&w, (void*)&z,
                     (void*)&w2a, (void*)&oa, (void*)&fl };
    hipLaunchCooperativeKernel((void*)mega, dim3(256), dim3(512), args, 0, stream);
  }
}

// Round 19
// 222.004 us; speedup vs baseline: 3.8333x; 3.8333x over previous
//
#include <hip/hip_runtime.h>
#include <hip/hip_bf16.h>
#include <math.h>

typedef unsigned short u16;
typedef short bf16x8 __attribute__((ext_vector_type(8)));
typedef float f32x4 __attribute__((ext_vector_type(4)));
typedef float f32x16 __attribute__((ext_vector_type(16)));

// software RNE (used in cold prep path; reference-identical)
__device__ __forceinline__ u16 f2b(float f){
  union { float f; unsigned u; } c; c.f = f;
  unsigned u = c.u;
  unsigned r = (u + 0x7fffu + ((u >> 16) & 1u)) >> 16;
  return (u16)r;
}
// hardware RNE via __bf16 cast (v_cvt_pk_bf16_f32 on gfx950) — same rounding
__device__ __forceinline__ u16 f2bh(float f){
  union { __bf16 b; u16 u; } c; c.b = (__bf16)f; return c.u;
}
__device__ __forceinline__ unsigned pack2(float a, float b){
  return (unsigned)f2bh(a) | ((unsigned)f2bh(b) << 16);
}
__device__ __forceinline__ float gelu_f(float x){
  return 0.5f * x * (1.0f + erff(x * 0.70710678118654752f));
}

// ---------------------------------------------------------------------------
// Weight prep (proven). Elementwise blocks 0..311 write bf16 B-fragment
// order: chunk for (n,k): ((((n>>4)*4+(k>>5))*4+((k>>3)&3))*16+(n&15))*8+(k&7).
// wT elem offsets: Wproj@0 | Wq@16384 (x 1/sqrt(128)) | Wk@147456 |
// W~=Wv@Wh @278528 (MFMA blocks 312..319) | Wfc@540672 | Wc@573440.
// ---------------------------------------------------------------------------
__global__ __launch_bounds__(256) void prep_weights(
    const float* __restrict__ Wproj, const float* __restrict__ Wq,
    const float* __restrict__ Wk,    const float* __restrict__ Wv,
    const float* __restrict__ Whp,   const float* __restrict__ Wfc,
    const float* __restrict__ Wc,    u16* __restrict__ wT)
{
  __shared__ __align__(16) u16 Ah[128*136];   // Wh_h^T : [n][d]
  __shared__ __align__(16) u16 Bv[128*136];   // Wv_h   : [k][d]
  int bid = blockIdx.x, tid = threadIdx.x;
  if (bid < 312) {
    int cid = bid * 256 + tid;
    if (cid >= 34816 && cid < 67584) return;   // W~ region written by MFMA blocks
    int region, lh = 0, c;
    if      (cid < 2048)  { region = 0; c = cid; }
    else if (cid < 18432) { int o = cid - 2048;  region = 1; lh = o >> 11; c = o & 2047; }
    else if (cid < 34816) { int o = cid - 18432; region = 2; lh = o >> 11; c = o & 2047; }
    else if (cid < 71680) { int o = cid - 67584; region = 5; lh = o >> 11; c = o & 2047; }
    else                  { int o = cid - 71680; region = 6; lh = o >> 11; c = o & 2047; }
    int l16 = c & 15, quad = (c >> 4) & 3, ks = (c >> 6) & 3, nt = c >> 8;
    int n = nt * 16 + l16, kb = ks * 32 + quad * 8;
    int l = lh >> 2, hh = lh & 3;
    const float rs = 0.08838834764831845f;
    u16 tmp[8];
#pragma unroll
    for (int e = 0; e < 8; ++e) {
      int k = kb + e;
      float v;
      switch (region) {
        case 0: v = Wproj[k * 128 + n]; break;
        case 1: v = Wq[l * 65536 + k * 512 + hh * 128 + n] * rs; break;
        case 2: v = Wk[l * 65536 + k * 512 + hh * 128 + n]; break;
        case 5: v = Wfc[lh * 16384 + k * 128 + n]; break;
        default: v = Wc[k * 512 + lh * 128 + n]; break;
      }
      tmp[e] = f2b(v);
    }
    *(uint4*)(wT + (size_t)cid * 8) = *(uint4*)tmp;
    return;
  }
  // ---- W~_h^T = Wh_h^T @ Wv_h^T via bf16 MFMA (one block per (l,h)) ----
  int lhb = bid - 312; int l = lhb >> 2, hh = lhb & 3;
#pragma unroll
  for (int it = 0; it < 64; ++it) {
    int idx = it * 256 + tid;
    int a = idx & 127, b = idx >> 7;
    Ah[a * 136 + b] = f2b(Whp[l * 65536 + (hh * 128 + b) * 128 + a]);  // [n=a][d=b]
    Bv[b * 136 + a] = f2b(Wv[l * 65536 + b * 512 + hh * 128 + a]);     // [k=b][d=a]
  }
  __syncthreads();
  int wv = tid >> 6, lane = tid & 63, quad = lane >> 4, l16 = lane & 15;
  f32x4 acc[2][8] = {};
  for (int ks = 0; ks < 4; ++ks) {
    bf16x8 aF[2], bF[8];
#pragma unroll
    for (int i = 0; i < 2; ++i)
      aF[i] = *(const bf16x8*)(Ah + ((wv*2+i)*16 + l16)*136 + ks*32 + quad*8);
#pragma unroll
    for (int n = 0; n < 8; ++n)
      bF[n] = *(const bf16x8*)(Bv + (n*16 + l16)*136 + ks*32 + quad*8);
#pragma unroll
    for (int i = 0; i < 2; ++i)
#pragma unroll
      for (int n = 0; n < 8; ++n)
        acc[i][n] = __builtin_amdgcn_mfma_f32_16x16x32_bf16(aF[i], bF[n], acc[i][n], 0, 0, 0);
  }
  size_t base = 278528 + (size_t)lhb * 16384;
#pragma unroll
  for (int i = 0; i < 2; ++i)
#pragma unroll
    for (int n2 = 0; n2 < 8; ++n2)
#pragma unroll
      for (int g = 0; g < 4; ++g) {
        int n = (wv*2+i)*16 + quad*4 + g;   // row of W~^T
        int k = n2*16 + l16;                // col
        wT[base + (size_t)((((n>>4)*4 + (k>>5))*4 + ((k>>3)&3))*16 + (n&15))*8 + (k&7)]
            = f2b(acc[i][n2][g]);
      }
}

// ---------------------------------------------------------------------------
// Trunk helpers (512 thr / 8 waves). Wave grid 4x2: wave = 2 m-tiles (wr) x
// 4 n-tiles (wc) -> aF reuse 2x, 8 B-chunks + 2 LDS loads per 8 MFMAs.
// A from LDS (pitch 136), B fragment-direct from L2.
// ---------------------------------------------------------------------------
__device__ __forceinline__ void gemm_g(const u16* A, const u16* __restrict__ Bg,
    f32x4 (*acc)[4], int wr, int wc, int quad, int l16, int lane){
#pragma unroll
  for (int ks = 0; ks < 4; ++ks){
    bf16x8 aF[2], bF[4];
#pragma unroll
    for (int i = 0; i < 2; ++i)
      aF[i] = *(const bf16x8*)(A + ((wr*2+i)*16 + l16)*136 + ks*32 + quad*8);
#pragma unroll
    for (int n = 0; n < 4; ++n)
      bF[n] = *(const bf16x8*)(Bg + ((size_t)(((wc*4+n)*4 + ks)*64 + lane))*8);
#pragma unroll
    for (int i = 0; i < 2; ++i)
#pragma unroll
      for (int n = 0; n < 4; ++n)
        acc[i][n] = __builtin_amdgcn_mfma_f32_16x16x32_bf16(aF[i], bF[n], acc[i][n], 0, 0, 0);
  }
}

__device__ __forceinline__ void write_rm(u16* dst, f32x4 (*acc)[4],
                                         int wr, int wc, int quad, int l16){
#pragma unroll
  for (int i = 0; i < 2; ++i)
#pragma unroll
    for (int n = 0; n < 4; ++n)
#pragma unroll
      for (int g = 0; g < 4; ++g)
        dst[((wr*2+i)*16 + quad*4 + g)*136 + (wc*4+n)*16 + l16] = f2bh(acc[i][n][g]);
}

__device__ __forceinline__ void write_tr(u16* dst, f32x4 (*acc)[4],
                                         int wr, int wc, int quad, int l16){
#pragma unroll
  for (int i = 0; i < 2; ++i)
#pragma unroll
    for (int n = 0; n < 4; ++n)
#pragma unroll
      for (int g = 0; g < 4; ++g)
        dst[((wc*4+n)*16 + l16)*136 + (wr*2+i)*16 + quad*4 + g] = f2bh(acc[i][n][g]);
}

__device__ __forceinline__ void block_reduce2(float &s1, float &s2,
                                              float* red, int wv, int lane){
#pragma unroll
  for (int off = 1; off < 64; off <<= 1){
    s1 += __shfl_xor(s1, off, 64);
    s2 += __shfl_xor(s2, off, 64);
  }
  if (lane == 0){ red[wv*2] = s1; red[wv*2+1] = s2; }
  __syncthreads();
  s1 = red[0]+red[2]+red[4]+red[6]+red[8]+red[10]+red[12]+red[14];
  s2 = red[1]+red[3]+red[5]+red[7]+red[9]+red[11]+red[13]+red[15];
  __syncthreads();
}

// ---------------------------------------------------------------------------
// Set-local trunk (proven R16): rolled layer/head loops (I-cache), Wh folded
// into W~ (v' = h@W~; PV accumulates into aR), 3 syncs/head, HW bf16 converts
// + __expf, z written in 32x32x16 fragment-chunk order for op-direct cross.
// ---------------------------------------------------------------------------
__global__ __launch_bounds__(512, 2) void trunk(
    const float* __restrict__ x, const int* __restrict__ xsize,
    const u16* __restrict__ wT, u16* __restrict__ zg)
{
  __shared__ __align__(16) u16 hA[128*136];
  __shared__ __align__(16) u16 qP[128*136];
  __shared__ __align__(16) u16 kB[128*136];
  __shared__ __align__(16) u16 vB[128*136];
  __shared__ float svalid[128];
  __shared__ float red[16];
  int tid = threadIdx.x;
  int wv = tid >> 6, lane = tid & 63, quad = lane >> 4, l16 = lane & 15;
  int wr = wv >> 1, wc = wv & 1;
  int s = blockIdx.x;
  int sz = xsize[s]; if (sz < 1) sz = 1;
  int Mt = (sz + 15) >> 4, Mk = (sz + 31) >> 5;
  float den = (float)sz * 128.0f;

  // ---- stage x -> hA (bf16) + row validity ----
#pragma unroll
  for (int it = 0; it < 4; ++it) {
    int ch = tid + it * 512; int r = ch >> 4, cc = ch & 15;
    const float* p = x + ((size_t)s * 128 + r) * 128 + cc * 8;
    float4 u0 = *(const float4*)p, u1 = *(const float4*)(p + 4);
    int nz = (u0.x!=0.f)|(u0.y!=0.f)|(u0.z!=0.f)|(u0.w!=0.f)|
             (u1.x!=0.f)|(u1.y!=0.f)|(u1.z!=0.f)|(u1.w!=0.f);
    nz |= __shfl_xor(nz,1,64); nz |= __shfl_xor(nz,2,64);
    nz |= __shfl_xor(nz,4,64); nz |= __shfl_xor(nz,8,64);
    if ((tid & 15) == 0) svalid[r] = nz ? 1.f : 0.f;
    uint4 w;
    w.x = pack2(u0.x,u0.y); w.y = pack2(u0.z,u0.w);
    w.z = pack2(u1.x,u1.y); w.w = pack2(u1.z,u1.w);
    *(uint4*)(hA + r*136 + cc*8) = w;
  }
  __syncthreads();

  // ---- proj: h0 = gelu(x @ Wproj) * mask ----
  f32x4 hR[2][4];
  {
    f32x4 acc[2][4] = {};
    gemm_g(hA, wT, acc, wr, wc, quad, l16, lane);
    __syncthreads();                     // hA reads done before overwrite
#pragma unroll
    for (int i = 0; i < 2; ++i)
#pragma unroll
      for (int n = 0; n < 4; ++n)
#pragma unroll
        for (int g = 0; g < 4; ++g) {
          int row = (wr*2+i)*16 + quad*4 + g;
          float gg = gelu_f(acc[i][n][g]) * svalid[row];
          hR[i][n][g] = gg;
          hA[row*136 + (wc*4+n)*16 + l16] = f2bh(gg);
        }
    __syncthreads();                     // hA (h0) staged
  }

#pragma unroll 1
  for (int l = 0; l < 2; ++l) {
    f32x4 aR[2][4] = {};
#pragma unroll 1
    for (int hh = 0; hh < 4; ++hh) {
      int lh = l * 4 + hh;
      {
        f32x4 qa[2][4] = {};
        gemm_g(hA, wT + 16384 + lh*16384, qa, wr, wc, quad, l16, lane);
        write_rm(qP, qa, wr, wc, quad, l16);
      }
      {
        f32x4 ka[2][4] = {};
        gemm_g(hA, wT + 147456 + lh*16384, ka, wr, wc, quad, l16, lane);
        write_rm(kB, ka, wr, wc, quad, l16);
      }
      {
        f32x4 va[2][4] = {};
        gemm_g(hA, wT + 278528 + lh*16384, va, wr, wc, quad, l16, lane);
        write_tr(vB, va, wr, wc, quad, l16);   // v'^T : [out-col][key]
      }
      __syncthreads();                   // S_b: q,k,v'T staged
      // ---- QK^T + masked softmax: wave wv owns full rows of m-tile wv ----
      if (wv < Mt) {
        bf16x8 qA[4];
#pragma unroll
        for (int ks = 0; ks < 4; ++ks)
          qA[ks] = *(const bf16x8*)(qP + (wv*16 + l16)*136 + ks*32 + quad*8);
        f32x4 sacc[8] = {};
#pragma unroll
        for (int ks = 0; ks < 4; ++ks) {
          bf16x8 bF[8];
#pragma unroll
          for (int j = 0; j < 8; ++j)
            if (j < Mt) bF[j] = *(const bf16x8*)(kB + (j*16+l16)*136 + ks*32 + quad*8);
#pragma unroll
          for (int j = 0; j < 8; ++j)
            if (j < Mt) sacc[j] = __builtin_amdgcn_mfma_f32_16x16x32_bf16(qA[ks], bF[j], sacc[j], 0, 0, 0);
        }
        for (int g = 0; g < 4; ++g) {
          float vals[8]; float rmax = -1e30f;
#pragma unroll
          for (int j = 0; j < 8; ++j)
            if (j < Mt) {
              float v = sacc[j][g];
              vals[j] = v;
              rmax = fmaxf(rmax, v);
            }
          for (int off = 1; off < 16; off <<= 1) rmax = fmaxf(rmax, __shfl_xor(rmax, off, 64));
          if (sz < 128) rmax = fmaxf(rmax, 0.0f);   // ref max includes pad zeros
          float rsum = 0.f;
#pragma unroll
          for (int j = 0; j < 8; ++j)
            if (j < Mt) {
              float e = (vals[j] != 0.0f) ? __expf(vals[j] - rmax) : 0.0f;
              vals[j] = e; rsum += e;
            }
          for (int off = 1; off < 16; off <<= 1) rsum += __shfl_xor(rsum, off, 64);
          float inv = 1.0f / (rsum + 1e-10f);
#pragma unroll
          for (int j = 0; j < 8; ++j)
            if (j < Mt) sacc[j][g] = vals[j] * inv;
        }
        // P -> LDS rows of m-tile wv
#pragma unroll
        for (int j = 0; j < 8; ++j)
          if (j < Mt)
#pragma unroll
            for (int g = 0; g < 4; ++g)
              qP[(wv*16 + quad*4 + g)*136 + j*16 + l16] = f2bh(sacc[j][g]);
      }
      __syncthreads();                   // S_c: P staged (cross-wave PV reads)
      // ---- PV: aR += P @ v' (stale P cols beyond Mt*16 hit zero v' rows) --
#pragma unroll
      for (int i = 0; i < 2; ++i) {
        int mtile = wr*2 + i;
        if (mtile < Mt) {
          for (int ks = 0; ks < Mk; ++ks) {
            bf16x8 aF = *(const bf16x8*)(qP + (mtile*16 + l16)*136 + ks*32 + quad*8);
            bf16x8 bF[4];
#pragma unroll
            for (int n = 0; n < 4; ++n)
              bF[n] = *(const bf16x8*)(vB + ((wc*4+n)*16+l16)*136 + ks*32 + quad*8);
#pragma unroll
            for (int n = 0; n < 4; ++n)
              aR[i][n] = __builtin_amdgcn_mfma_f32_16x16x32_bf16(aF, bF[n], aR[i][n], 0, 0, 0);
          }
        }
      }
      __syncthreads();                   // S_a: PV reads done; buffers free
    } // heads

    // ---- set_norm(h + a) ----
    {
      float ls1 = 0.f, ls2 = 0.f;
#pragma unroll
      for (int i = 0; i < 2; ++i)
#pragma unroll
        for (int n = 0; n < 4; ++n)
#pragma unroll
          for (int g = 0; g < 4; ++g) {
            int row = (wr*2+i)*16 + quad*4 + g;
            float u = hR[i][n][g] + aR[i][n][g] * svalid[row];
            hR[i][n][g] = u;
            ls1 += u; ls2 += u * u;
          }
      block_reduce2(ls1, ls2, red, wv, lane);
      float mean = ls1 / den;
      float var = ls2 / den - mean * mean; if (var < 0.f) var = 0.f;
      float inv = 1.0f / (sqrtf(var) + 1e-8f);
#pragma unroll
      for (int i = 0; i < 2; ++i)
#pragma unroll
        for (int n = 0; n < 4; ++n)
#pragma unroll
          for (int g = 0; g < 4; ++g) {
            int row = (wr*2+i)*16 + quad*4 + g;
            float hn = (hR[i][n][g] - mean) * inv * svalid[row];
            hR[i][n][g] = hn;
            hA[row*136 + (wc*4+n)*16 + l16] = f2bh(hn);
          }
      __syncthreads();                   // hA (normalized) staged
    }
    // ---- set_norm(h + gelu(h @ Wfc) * mask) ----
    {
      f32x4 fa[2][4] = {};
      gemm_g(hA, wT + 540672 + l*16384, fa, wr, wc, quad, l16, lane);
      float ls1 = 0.f, ls2 = 0.f;
#pragma unroll
      for (int i = 0; i < 2; ++i)
#pragma unroll
        for (int n = 0; n < 4; ++n)
#pragma unroll
          for (int g = 0; g < 4; ++g) {
            int row = (wr*2+i)*16 + quad*4 + g;
            float u = hR[i][n][g] + gelu_f(fa[i][n][g]) * svalid[row];
            hR[i][n][g] = u;
            ls1 += u; ls2 += u * u;
          }
      block_reduce2(ls1, ls2, red, wv, lane);   // first sync fences hA reads
      float mean = ls1 / den;
      float var = ls2 / den - mean * mean; if (var < 0.f) var = 0.f;
      float inv = 1.0f / (sqrtf(var) + 1e-8f);
#pragma unroll
      for (int i = 0; i < 2; ++i)
#pragma unroll
        for (int n = 0; n < 4; ++n)
#pragma unroll
          for (int g = 0; g < 4; ++g) {
            int row = (wr*2+i)*16 + quad*4 + g;
            float hn = (hR[i][n][g] - mean) * inv * svalid[row];
            hR[i][n][g] = hn;
            hA[row*136 + (wc*4+n)*16 + l16] = f2bh(hn);
          }
      __syncthreads();                   // hA staged for next layer / z
    }
  } // layers

  // ---- z_h = h @ Wc_h -> global in 32x32x16 FRAGMENT-CHUNK order ----
#pragma unroll 1
  for (int hh = 0; hh < 4; ++hh) {
    f32x4 za[2][4] = {};
    gemm_g(hA, wT + 573440 + hh*16384, za, wr, wc, quad, l16, lane);
    u16* zb = zg + (((size_t)s*4 + hh) << 14);
#pragma unroll
    for (int i = 0; i < 2; ++i)
#pragma unroll
      for (int n = 0; n < 4; ++n)
#pragma unroll
        for (int g = 0; g < 4; ++g) {
          int row = (wr*2+i)*16 + quad*4 + g;
          int col = (wc*4+n)*16 + l16;
          // chunk map: ((row>>5)*8 + (col>>4))*512 + ((col>>3)&1)*256
          //            + (row&31)*8 + (col&7)
          zb[(size_t)(((row>>5)*8 + (col>>4))*512 + ((col>>3)&1)*256
                      + (row&31)*8 + (col&7))] = f2bh(za[i][n][g]);
        }
  }
}

// ---------------------------------------------------------------------------
// Cross-set v2 (proven): operand-direct from global (z is in fragment-chunk
// order). No LDS staging, no syncs until the 16-B reduce. Enumerated (j<=i)
// pairs x 4 heads = 4704 blocks; 4 waves each 2x2 of 32x32x16 tiles,
// size-trimmed loads + MFMA + epilogue. leaky = 0.65x + 0.35|x|.
// ---------------------------------------------------------------------------
__global__ __launch_bounds__(256) void cross_kernel(
    const u16* __restrict__ zg, float* __restrict__ Tbuf, const int* __restrict__ xsize)
{
  __shared__ float red[4];
  int tid = threadIdx.x, wave = tid >> 6, lane = tid & 63;
  int t4 = blockIdx.x;
  int pr = t4 >> 2, hh = t4 & 3;
  float jf = (97.0f - sqrtf(9409.0f - 8.0f * (float)pr)) * 0.5f;
  int j = (int)jf; if (j > 47) j = 47; if (j < 0) j = 0;
  while (j > 0 && j * 48 - (j * (j - 1)) / 2 > pr) --j;
  while ((j + 1) * 48 - ((j + 1) * j) / 2 <= pr) ++j;
  int i = j + pr - (j * 48 - (j * (j - 1)) / 2);
  int sj = xsize[j]; if (sj < 1) sj = 1;
  int si = xsize[i]; if (si < 1) si = 1;
  int MjT = (sj + 31) >> 5, MiT = (si + 31) >> 5;
  const u16* zj = zg + (((size_t)j * 4 + hh) << 14);
  const u16* zi = zg + (((size_t)i * 4 + hh) << 14);
  int gA = (wave >> 1) * 2, gB = (wave & 1) * 2;
  bool a0 = gA < MjT, a1 = (gA + 1) < MjT;
  bool b0 = gB < MiT, b1 = (gB + 1) < MiT;
  f32x16 acc[2][2] = {};
  if ((a0 || a1) && (b0 || b1)) {
#pragma unroll
    for (int ks = 0; ks < 8; ++ks) {
      bf16x8 aF[2], bF[2];
      if (a0) aF[0] = *(const bf16x8*)(zj + (size_t)((gA    )*8 + ks)*512 + lane*8);
      if (a1) aF[1] = *(const bf16x8*)(zj + (size_t)((gA + 1)*8 + ks)*512 + lane*8);
      if (b0) bF[0] = *(const bf16x8*)(zi + (size_t)((gB    )*8 + ks)*512 + lane*8);
      if (b1) bF[1] = *(const bf16x8*)(zi + (size_t)((gB + 1)*8 + ks)*512 + lane*8);
      if (a0 && b0) acc[0][0] = __builtin_amdgcn_mfma_f32_32x32x16_bf16(aF[0], bF[0], acc[0][0], 0, 0, 0);
      if (a0 && b1) acc[0][1] = __builtin_amdgcn_mfma_f32_32x32x16_bf16(aF[0], bF[1], acc[0][1], 0, 0, 0);
      if (a1 && b0) acc[1][0] = __builtin_amdgcn_mfma_f32_32x32x16_bf16(aF[1], bF[0], acc[1][0], 0, 0, 0);
      if (a1 && b1) acc[1][1] = __builtin_amdgcn_mfma_f32_32x32x16_bf16(aF[1], bF[1], acc[1][1], 0, 0, 0);
    }
  }
  float s1 = 0.f, s2 = 0.f;
#pragma unroll
  for (int ii = 0; ii < 2; ++ii)
#pragma unroll
    for (int jj = 0; jj < 2; ++jj) {
      bool tact = (ii ? a1 : a0) && (jj ? b1 : b0);
      if (tact)
#pragma unroll
        for (int r = 0; r < 16; ++r) {
          float a = acc[ii][jj][r];
          s1 += a; s2 += fabsf(a);
        }
    }
  const float rs = 0.08838834764831845f;
  float tp = rs * (0.65f * s1 + 0.35f * s2);
  for (int off = 1; off < 64; off <<= 1) tp += __shfl_xor(tp, off, 64);
  if (lane == 0) red[wave] = tp;
  __syncthreads();
  if (tid == 0)
    Tbuf[((j * 48 + i) << 2) + hh] = red[0] + red[1] + red[2] + red[3];
}

// out[a][b] = sum_h T[min,max,h] * w2[h] / (size_b * 128)
__global__ __launch_bounds__(256) void final_kernel(
    const float* __restrict__ Tbuf, const float* __restrict__ w2,
    const int* __restrict__ xsize, float* __restrict__ out)
{
  int idx = blockIdx.x * 256 + threadIdx.x;
  if (idx >= 2304) return;
  int a = idx / 48, b = idx - a * 48;
  int j = a < b ? a : b, i = a < b ? b : a;
  float t = 0.f;
  for (int h = 0; h < 4; ++h) t += Tbuf[((j * 48 + i) << 2) + h] * w2[h];
  int szb = xsize[b]; if (szb < 1) szb = 1;
  out[idx] = t / ((float)szb * 128.0f);
}

// ---------------------------------------------------------------------------
extern "C" void kernel_launch(void* const* d_in, const int* in_sizes, int n_in,
                              void* d_out, int out_size, void* d_ws, size_t ws_size,
                              hipStream_t stream)
{
  const float* x     = (const float*)d_in[0];
  const int*   xsize = (const int*)d_in[1];
  const float* Wproj = (const float*)d_in[2];
  const float* Wq    = (const float*)d_in[3];
  const float* Wk    = (const float*)d_in[4];
  const float* Wv    = (const float*)d_in[5];
  const float* Whp   = (const float*)d_in[6];
  const float* Wfc   = (const float*)d_in[7];
  const float* Wc    = (const float*)d_in[8];
  const float* w2    = (const float*)d_in[9];
  float* out = (float*)d_out;

  char* ws = (char*)d_ws;
  size_t off = 0;
  auto alloc = [&](size_t bytes) -> char* {
    char* p = ws + off;
    off += (bytes + 255) & ~(size_t)255;
    return p;
  };
  u16*   wT   = (u16*)  alloc(638976 * 2);
  float* Tbuf = (float*)alloc(9216 * 4);
  u16*   zg   = (u16*)  alloc((size_t)3145728 * 2);

  prep_weights<<<320, 256, 0, stream>>>(Wproj, Wq, Wk, Wv, Whp, Wfc, Wc, wT);
  trunk<<<48, 512, 0, stream>>>(x, xsize, wT, zg);
  cross_kernel<<<4704, 256, 0, stream>>>(zg, Tbuf, xsize);
  final_kernel<<<9, 256, 0, stream>>>(Tbuf, w2, xsize, out);
}